// Round 1
// baseline (1354.305 us; speedup 1.0000x reference)
//
#include <hip/hip_runtime.h>
#include <cstdint>

typedef unsigned short u16;
typedef __attribute__((ext_vector_type(8))) __bf16 bf16x8;
typedef __attribute__((ext_vector_type(4))) float f32x4;
typedef __attribute__((ext_vector_type(4))) unsigned short u16x4;

// round-to-nearest-even f32 -> bf16 bits (inputs are finite randn; no NaN path)
__device__ __forceinline__ u16 f2bf(float f) {
  unsigned u = __float_as_uint(f);
  u += 0x7fff + ((u >> 16) & 1);
  return (u16)(u >> 16);
}

__device__ __forceinline__ void g2l16(const void* g, void* l) {
  __builtin_amdgcn_global_load_lds(
      (const __attribute__((address_space(1))) unsigned int*)g,
      (__attribute__((address_space(3))) unsigned int*)l, 16, 0, 0);
}

// ---------------------------------------------------------------------------
// NT GEMM: C[m][n] = scale * sum_k A[m][k] * B[n][k]   (A,B bf16, acc f32)
// 128x128 tile, BK=32, 256 threads (4 waves, each 64x64 via 4x4 mfma 16x16x32)
// OUT_BF16: 1 -> store bf16, 0 -> store f32
// ---------------------------------------------------------------------------
template <int OUT_BF16>
__global__ void gemm_nt(const u16* __restrict__ A, const u16* __restrict__ B,
                        void* __restrict__ Cv,
                        int lda, int ldb, int ldc,
                        long sA, long sB, long sC,
                        int K, float scale)
{
  __shared__ char sm[16384];           // As 8KB | Bs 8KB, each 128 rows x 32 bf16
  char* As = sm;
  char* Bs = sm + 8192;
  const int t = threadIdx.x;
  const int z = blockIdx.z;
  const u16* Ab = A + (long)z * sA + (long)(blockIdx.y * 128) * lda;
  const u16* Bb = B + (long)z * sB + (long)(blockIdx.x * 128) * ldb;

  const int wave = t >> 6, lane = t & 63;
  const int lm = lane & 15, quad = lane >> 4;
  const int wm = (wave >> 1) * 64, wn = (wave & 1) * 64;

  f32x4 acc[4][4] = {};

  // staging: thread t loads 16B: row = t/4 (+64 for second call), col byte = (t&3)*16
  const int sr = t >> 2;
  const int sc = (t & 3) * 8;          // element offset
  const long aoff0 = (long)sr * lda + sc;
  const long aoff1 = (long)(sr + 64) * lda + sc;
  const long boff0 = (long)sr * ldb + sc;
  const long boff1 = (long)(sr + 64) * ldb + sc;
  char* lA0 = As + t * 16;  char* lA1 = As + 4096 + t * 16;
  char* lB0 = Bs + t * 16;  char* lB1 = Bs + 4096 + t * 16;

  for (int k0 = 0; k0 < K; k0 += 32) {
    __syncthreads();                    // previous iter's LDS reads done
    g2l16(Ab + aoff0 + k0, lA0);
    g2l16(Ab + aoff1 + k0, lA1);
    g2l16(Bb + boff0 + k0, lB0);
    g2l16(Bb + boff1 + k0, lB1);
    __syncthreads();                    // compiler drains vmcnt before s_barrier

    bf16x8 af[4], bg[4];
#pragma unroll
    for (int i = 0; i < 4; ++i) {
      af[i] = *(const bf16x8*)(As + ((wm + i * 16 + lm) * 32 + quad * 8) * 2);
      bg[i] = *(const bf16x8*)(Bs + ((wn + i * 16 + lm) * 32 + quad * 8) * 2);
    }
#pragma unroll
    for (int i = 0; i < 4; ++i)
#pragma unroll
      for (int j = 0; j < 4; ++j)
        acc[i][j] = __builtin_amdgcn_mfma_f32_16x16x32_bf16(af[i], bg[j], acc[i][j], 0, 0, 0);
  }

  // C/D layout (verified m89): col = lane&15, row = quad*4 + reg
  const int row0 = blockIdx.y * 128 + wm + quad * 4;
  const int col0 = blockIdx.x * 128 + wn + lm;
  if (OUT_BF16) {
    u16* C = (u16*)Cv + (long)z * sC;
#pragma unroll
    for (int i = 0; i < 4; ++i)
#pragma unroll
      for (int j = 0; j < 4; ++j)
#pragma unroll
        for (int r = 0; r < 4; ++r)
          C[(long)(row0 + i * 16 + r) * ldc + (col0 + j * 16)] = f2bf(acc[i][j][r] * scale);
  } else {
    float* C = (float*)Cv + (long)z * sC;
#pragma unroll
    for (int i = 0; i < 4; ++i)
#pragma unroll
      for (int j = 0; j < 4; ++j)
#pragma unroll
        for (int r = 0; r < 4; ++r)
          C[(long)(row0 + i * 16 + r) * ldc + (col0 + j * 16)] = acc[i][j][r] * scale;
  }
}

// ---------------------------------------------------------------------------
// Row softmax over 2048 cols, in-place f32, plus bf16 copy to P
// ---------------------------------------------------------------------------
__global__ void softmax_rows(float* __restrict__ S, u16* __restrict__ P)
{
  const long row = blockIdx.x;
  float* p = S + row * 2048;
  u16*  q = P + row * 2048;
  const int t = threadIdx.x;
  float4 v0 = ((const float4*)p)[t];
  float4 v1 = ((const float4*)p)[t + 256];

  float m = fmaxf(fmaxf(fmaxf(v0.x, v0.y), fmaxf(v0.z, v0.w)),
                  fmaxf(fmaxf(v1.x, v1.y), fmaxf(v1.z, v1.w)));
#pragma unroll
  for (int s = 32; s; s >>= 1) m = fmaxf(m, __shfl_xor(m, s));
  __shared__ float red[4];
  if ((t & 63) == 0) red[t >> 6] = m;
  __syncthreads();
  m = fmaxf(fmaxf(red[0], red[1]), fmaxf(red[2], red[3]));

  v0.x = __expf(v0.x - m); v0.y = __expf(v0.y - m);
  v0.z = __expf(v0.z - m); v0.w = __expf(v0.w - m);
  v1.x = __expf(v1.x - m); v1.y = __expf(v1.y - m);
  v1.z = __expf(v1.z - m); v1.w = __expf(v1.w - m);

  float s8 = ((v0.x + v0.y) + (v0.z + v0.w)) + ((v1.x + v1.y) + (v1.z + v1.w));
#pragma unroll
  for (int s = 32; s; s >>= 1) s8 += __shfl_xor(s8, s);
  __syncthreads();
  if ((t & 63) == 0) red[t >> 6] = s8;
  __syncthreads();
  s8 = red[0] + red[1] + red[2] + red[3];
  const float inv = 1.0f / s8;

  v0.x *= inv; v0.y *= inv; v0.z *= inv; v0.w *= inv;
  v1.x *= inv; v1.y *= inv; v1.z *= inv; v1.w *= inv;
  ((float4*)p)[t] = v0;
  ((float4*)p)[t + 256] = v1;
  u16x4 b0 = { f2bf(v0.x), f2bf(v0.y), f2bf(v0.z), f2bf(v0.w) };
  u16x4 b1 = { f2bf(v1.x), f2bf(v1.y), f2bf(v1.z), f2bf(v1.w) };
  ((u16x4*)q)[t] = b0;
  ((u16x4*)q)[t + 256] = b1;
}

// ---------------------------------------------------------------------------
// Per-batch transpose f32[2048][1024] -> bf16[1024][2048]
// ---------------------------------------------------------------------------
__global__ void transpose_cvt(const float* __restrict__ in, u16* __restrict__ out)
{
  __shared__ float tile[32][33];
  const int z = blockIdx.z;
  const float* ib = in + (long)z * 2048 * 1024;
  u16* ob = out + (long)z * 1024 * 2048;
  const int c0 = blockIdx.x * 32, r0 = blockIdx.y * 32;
  const int tx = threadIdx.x, ty = threadIdx.y;
#pragma unroll
  for (int k = 0; k < 32; k += 8)
    tile[ty + k][tx] = ib[(long)(r0 + ty + k) * 1024 + c0 + tx];
  __syncthreads();
#pragma unroll
  for (int k = 0; k < 32; k += 8)
    ob[(long)(c0 + ty + k) * 2048 + r0 + tx] = f2bf(tile[tx][ty + k]);
}

// ---------------------------------------------------------------------------
// f32 -> bf16 convert with output row-stride ldo (input has 1024 cols: shift 10)
// ---------------------------------------------------------------------------
__global__ void cvt_bf16(const float* __restrict__ in, u16* __restrict__ out,
                         int ldo, long n)
{
  long i = ((long)blockIdx.x * 256 + threadIdx.x) * 4;
  if (i >= n) return;
  float4 v = *(const float4*)(in + i);
  long row = i >> 10;
  int col = (int)(i & 1023);
  u16x4 b = { f2bf(v.x), f2bf(v.y), f2bf(v.z), f2bf(v.w) };
  *(u16x4*)(out + row * (long)ldo + col) = b;
}

extern "C" void kernel_launch(void* const* d_in, const int* in_sizes, int n_in,
                              void* d_out, int out_size, void* d_ws, size_t ws_size,
                              hipStream_t stream)
{
  (void)in_sizes; (void)n_in; (void)out_size; (void)ws_size;
  const float* query = (const float*)d_in[0];
  const float* bank  = (const float*)d_in[1];
  const float* Wc    = (const float*)d_in[2];
  const float* Woq   = (const float*)d_in[3];
  const float* Woc   = (const float*)d_in[4];

  const long B = 16, L = 2048, D = 1024;
  float* out  = (float*)d_out;                 // [B*L*D]
  float* attn = out + B * L * D;               // [B*L*L]

  // workspace layout (bytes): kb 67M | cpb 67M | kbT 67M | Acat 134M | Wcb 2M | Wcat 4M  = ~342MB
  u16* kb   = (u16*)d_ws;                      // bf16(bank)           [B][L][D]
  u16* cpb  = kb + B * L * D;                  // bf16(ctx_proj)       [B][L][D]
  u16* ab   = kb;                              // bf16(attn) — reuses kb+cpb (dead after G2)
  u16* kbT  = cpb + B * L * D;                 // bf16(bank^T)         [B][D][L]
  u16* Acat = kbT + B * D * L;                 // [context | query]    [B][L][2048]
  u16* Wcb  = Acat + B * L * 2048;             // bf16(Wc)             [D][D]
  u16* Wcat = Wcb + D * D;                     // [Woc | Woq]          [D][2048]

  const long nQ = B * L * D;                   // 33.5M
  const long nW = D * D;                       // 1M

  cvt_bf16<<<dim3((unsigned)(nQ / 4 / 256)), 256, 0, stream>>>(bank, kb, 1024, nQ);
  cvt_bf16<<<dim3((unsigned)(nQ / 4 / 256)), 256, 0, stream>>>(query, Acat + 1024, 2048, nQ);
  cvt_bf16<<<dim3((unsigned)(nW / 4 / 256)), 256, 0, stream>>>(Wc, Wcb, 1024, nW);
  cvt_bf16<<<dim3((unsigned)(nW / 4 / 256)), 256, 0, stream>>>(Woc, Wcat, 2048, nW);
  cvt_bf16<<<dim3((unsigned)(nW / 4 / 256)), 256, 0, stream>>>(Woq, Wcat + 1024, 2048, nW);
  transpose_cvt<<<dim3(32, 64, 16), dim3(32, 8), 0, stream>>>(bank, kbT);

  // G1: cpb[b] = kb[b] @ Wcb^T          M=2048 N=1024 K=1024
  gemm_nt<1><<<dim3(8, 16, 16), 256, 0, stream>>>(kb, Wcb, cpb,
      1024, 1024, 1024, L * D, 0, L * D, 1024, 1.0f);
  // G2: S[b] = query[b] @ cpb[b]^T / 32  M=2048 N=2048 K=1024  (A = query half of Acat)
  gemm_nt<0><<<dim3(16, 16, 16), 256, 0, stream>>>(Acat + 1024, cpb, attn,
      2048, 1024, 2048, L * 2048, L * D, L * 2048, 1024, 0.03125f);
  // softmax rows -> attn (f32, in place) + ab (bf16)
  softmax_rows<<<dim3((unsigned)(B * L)), 256, 0, stream>>>(attn, ab);
  // G4: context[b] = ab[b] @ bank[b]  (as NT vs kbT)  M=2048 N=1024 K=2048 -> Acat cols 0:1023
  gemm_nt<1><<<dim3(8, 16, 16), 256, 0, stream>>>(ab, kbT, Acat,
      2048, 2048, 2048, L * 2048, D * 2048, L * 2048, 2048, 1.0f);
  // G5: out[b] = Acat[b] @ Wcat^T       M=2048 N=1024 K=2048
  gemm_nt<0><<<dim3(8, 16, 16), 256, 0, stream>>>(Acat, Wcat, out,
      2048, 2048, 1024, L * 2048, 0, L * D, 2048, 1.0f);
}